// Round 2
// baseline (1151.876 us; speedup 1.0000x reference)
//
#include <hip/hip_runtime.h>
#include <hip/hip_bf16.h>

// Problem constants (SpiralDeblock): B=8, N_IN=7056, N_UP=28224, SEQ=9, CIN=64, COUT=32
namespace {
constexpr int kB    = 8;
constexpr int kNIn  = 7056;
constexpr int kNUp  = 28224;
constexpr int kSeq  = 9;
constexpr int kCin  = 64;
constexpr int kCout = 32;
constexpr int kE    = 3 * kNUp;      // 84672
constexpr int kF    = kSeq * kCin;   // 576
constexpr int kWStride = 326;        // LDS row stride (floats): %32==6 -> 2-way max, 8B aligned
}

// Kernel 1: pooled[b, row[e], :] += x[b, col[e], :] * val[e]   (f32 atomics)
// thread = (b, e, q), q indexes 16B (4-float) chunks of the 64-channel row
__global__ __launch_bounds__(256) void scatter_kernel(const float* __restrict__ x,
                                                      const float* __restrict__ val,
                                                      const int* __restrict__ row,
                                                      const int* __restrict__ col,
                                                      float* __restrict__ pool) {
    int t = blockIdx.x * blockDim.x + threadIdx.x;
    constexpr int total = kB * kE * 16;
    if (t >= total) return;
    int q  = t & 15;
    int be = t >> 4;
    int e  = be % kE;
    int b  = be / kE;
    int c  = col[e];
    int r  = row[e];
    float v = val[e];
    float4 xv = *reinterpret_cast<const float4*>(x + ((size_t)(b * kNIn + c) * kCin + q * 4));
    float* dst = pool + ((size_t)(b * kNUp + r) * kCin + q * 4);
    atomicAdd(dst + 0, xv.x * v);
    atomicAdd(dst + 1, xv.y * v);
    atomicAdd(dst + 2, xv.z * v);
    atomicAdd(dst + 3, xv.w * v);
}

// Kernel 2: out[b,n,o] = relu( sum_s sum_c pooled[b, idx[n,s], c] * W[s*64+c, o] + b[o] )
// block = 32 consecutive rows (single batch b per block; N_UP % 32 == 0) x 32 outs.
// thread: o = t&31, r0 = t>>5; computes rows r0, r0+8, r0+16, r0+24 (W regs reused x4).
// W (73.7 KB f32) staged in LDS in two s-phases of <=320 f each (41.7 KB).
__global__ __launch_bounds__(256) void gemm_kernel(const float* __restrict__ pool,
                                                   const float* __restrict__ W,
                                                   const float* __restrict__ bias,
                                                   const int* __restrict__ indices,
                                                   float* __restrict__ out) {
    __shared__ float Ws[kCout][kWStride];  // [o][f-within-phase]

    int t  = threadIdx.x;
    int o  = t & 31;
    int r0 = t >> 5;
    int base = blockIdx.x * 32;
    int b  = base / kNUp;               // whole block is one batch
    int n0 = base - b * kNUp;
    const float* poolb = pool + (size_t)b * kNUp * kCin;

    float acc[4] = {0.f, 0.f, 0.f, 0.f};
    float bias_f = bias[o];

    for (int phase = 0; phase < 2; ++phase) {
        int s0 = phase ? 5 : 0;
        int s1 = phase ? 9 : 5;
        int f0 = s0 * kCin;
        int nf = (s1 - s0) * kCin;      // 320 or 256
        if (phase) __syncthreads();     // all reads of previous Ws done
        for (int i = t; i < nf * kCout; i += 256) {  // coalesced: o fastest in W
            int f  = i >> 5;
            int oo = i & 31;
            Ws[oo][f] = W[(f0 + f) * kCout + oo];
        }
        __syncthreads();

        for (int s = s0; s < s1; ++s) {
            const float* pp[4];
#pragma unroll
            for (int k = 0; k < 4; ++k) {
                int n   = n0 + r0 + 8 * k;
                int idx = indices[n * kSeq + s];
                pp[k] = poolb + (size_t)idx * kCin;
            }
#pragma unroll
            for (int c4 = 0; c4 < kCin / 4; ++c4) {
                int f = (s - s0) * kCin + c4 * 4;
                float2 w01 = *reinterpret_cast<const float2*>(&Ws[o][f]);
                float2 w23 = *reinterpret_cast<const float2*>(&Ws[o][f + 2]);
#pragma unroll
                for (int k = 0; k < 4; ++k) {
                    float4 p = reinterpret_cast<const float4*>(pp[k])[c4];
                    acc[k] = fmaf(p.x, w01.x, acc[k]);
                    acc[k] = fmaf(p.y, w01.y, acc[k]);
                    acc[k] = fmaf(p.z, w23.x, acc[k]);
                    acc[k] = fmaf(p.w, w23.y, acc[k]);
                }
            }
        }
    }

#pragma unroll
    for (int k = 0; k < 4; ++k) {
        int R = base + r0 + 8 * k;
        out[(size_t)R * kCout + o] = fmaxf(acc[k] + bias_f, 0.0f);
    }
}

extern "C" void kernel_launch(void* const* d_in, const int* in_sizes, int n_in,
                              void* d_out, int out_size, void* d_ws, size_t ws_size,
                              hipStream_t stream) {
    const float* x    = (const float*)d_in[0];
    const float* val  = (const float*)d_in[1];
    const float* W    = (const float*)d_in[2];
    const float* bias = (const float*)d_in[3];
    const int* row     = (const int*)d_in[4];
    const int* col     = (const int*)d_in[5];
    const int* indices = (const int*)d_in[6];
    float* out = (float*)d_out;

    float* pool = (float*)d_ws;
    size_t pool_bytes = (size_t)kB * kNUp * kCin * sizeof(float);  // 57.8 MB
    hipMemsetAsync(d_ws, 0, pool_bytes, stream);

    constexpr int total = kB * kE * 16;
    scatter_kernel<<<(total + 255) / 256, 256, 0, stream>>>(x, val, row, col, pool);

    gemm_kernel<<<kB * kNUp / 32, 256, 0, stream>>>(pool, W, bias, indices, out);
}

// Round 3
// 205.927 us; speedup vs baseline: 5.5936x; 5.5936x over previous
//
#include <hip/hip_runtime.h>
#include <hip/hip_bf16.h>

// SpiralDeblock: B=8, N_IN=7056, N_UP=28224, SEQ=9, CIN=64, COUT=32
namespace {
constexpr int kB    = 8;
constexpr int kNIn  = 7056;
constexpr int kNUp  = 28224;
constexpr int kSeq  = 9;
constexpr int kCin  = 64;
constexpr int kCout = 32;
constexpr int kE    = 3 * kNUp;          // 84672
constexpr int kMRows = kB * kNUp;        // 225792
constexpr int kTilesPerB = kNUp / 16;    // 1764 (exact -> tiles never straddle batches)
constexpr int kWFragN = 18 * 2 * 64 * 8; // 18432 bf16 values

// ws layout (bytes), all 16B-aligned
constexpr size_t kOffPool  = 0;                         // bf16 pooled: 8*28224*64*2 = 28,901,376
constexpr size_t kOffWfrag = 28901376;                  // 36,864
constexpr size_t kOffCnt   = kOffWfrag + 36864;         // 112,896
constexpr size_t kOffOffs  = kOffCnt + 112896;
constexpr size_t kOffCur   = kOffOffs + 112896;
constexpr size_t kOffEl    = kOffCur + 112896;          // E*8 = 677,376  (total ~30 MB)
}

typedef __attribute__((ext_vector_type(8))) short short8;
typedef __attribute__((ext_vector_type(4))) float f32x4;

__device__ __forceinline__ unsigned short f32_to_bf16(float f) {  // RNE
    unsigned int u = __float_as_uint(f);
    u += 0x7fffu + ((u >> 16) & 1u);
    return (unsigned short)(u >> 16);
}

// --- CSR build: invert row[] ---------------------------------------------
__global__ void hist_kernel(const int* __restrict__ row, int* __restrict__ cnt) {
    int e = blockIdx.x * 256 + threadIdx.x;
    if (e < kE) atomicAdd(&cnt[row[e]], 1);
}

// single block, 1024 threads: exclusive prefix sum of cnt -> offs, cursor
__global__ __launch_bounds__(1024) void scan_kernel(const int* __restrict__ cnt,
                                                    int* __restrict__ offs,
                                                    int* __restrict__ cursor) {
    __shared__ int part[1024];
    int t = threadIdx.x;
    int lo = t * 28, hi = min(lo + 28, kNUp);
    int s = 0;
    for (int i = lo; i < hi; ++i) s += cnt[i];
    part[t] = s;
    __syncthreads();
    for (int off = 1; off < 1024; off <<= 1) {
        int v = (t >= off) ? part[t - off] : 0;
        __syncthreads();
        part[t] += v;
        __syncthreads();
    }
    int base = (t == 0) ? 0 : part[t - 1];
    for (int i = lo; i < hi; ++i) {
        offs[i] = base;
        cursor[i] = base;
        base += cnt[i];
    }
}

__global__ void fill_kernel(const int* __restrict__ row, const int* __restrict__ col,
                            const float* __restrict__ val, int* __restrict__ cursor,
                            uint2* __restrict__ elist) {
    int e = blockIdx.x * 256 + threadIdx.x;
    if (e >= kE) return;
    int r = row[e];
    int slot = atomicAdd(&cursor[r], 1);
    elist[slot] = make_uint2((unsigned)col[e], __float_as_uint(val[e]));
}

// --- pooled[b,r,c] = sum_{e in CSR[r]} x[b,col[e],c]*val[e], stored bf16 ---
// block = 4 rows x 64 channels; consecutive blocks share batch b (L2-friendly)
__global__ __launch_bounds__(256) void pool_gather(const float* __restrict__ x,
                                                   const int* __restrict__ offs,
                                                   const int* __restrict__ cnt,
                                                   const uint2* __restrict__ elist,
                                                   unsigned short* __restrict__ poolb) {
    int t = threadIdx.x;
    int c = t & 63;
    int rowid = blockIdx.x * 4 + (t >> 6);           // < B*N_UP
    int b = rowid / kNUp;
    int r = rowid - b * kNUp;
    const float* xb = x + (size_t)b * kNIn * kCin;
    int e0 = offs[r], n = cnt[r];
    float acc = 0.f;
    for (int k = 0; k < n; ++k) {
        uint2 ev = elist[e0 + k];                    // broadcast across the wave
        acc += xb[(size_t)ev.x * kCin + c] * __uint_as_float(ev.y);
    }
    poolb[(size_t)rowid * kCin + c] = f32_to_bf16(acc);
}

// --- W -> MFMA B-fragment order, bf16 ------------------------------------
// frag value (ks, ct, lane l, j) = W[ks*32 + (l>>4)*8 + j][ct*16 + (l&15)]
__global__ void wprep_kernel(const float* __restrict__ W, unsigned short* __restrict__ wfrag) {
    int i = blockIdx.x * 256 + threadIdx.x;
    if (i >= kWFragN) return;
    int j  = i & 7;
    int l  = (i >> 3) & 63;
    int ct = (i >> 9) & 1;
    int ks = i >> 10;                                // 0..17
    int k  = ks * 32 + (l >> 4) * 8 + j;
    int o  = ct * 16 + (l & 15);
    wfrag[i] = f32_to_bf16(W[k * kCout + o]);
}

// --- MFMA GEMM: out[R,o] = relu(sum_f spiral[R,f]*W[f,o] + bias[o]) -------
// 4 waves/block, 1 16-row M-tile per wave, both 16-col tiles; K=576 in 18 chunks of 32.
// A lane map (16x16x32): lane l holds A[l&15][(l>>4)*8 + j] -> one 16B global load.
// C lane map (verified): col = l&15, row = (l>>4)*4 + reg.
__global__ __launch_bounds__(256) void gemm_mfma(const unsigned short* __restrict__ poolb,
                                                 const unsigned short* __restrict__ wfrag,
                                                 const float* __restrict__ bias,
                                                 const int* __restrict__ indices,
                                                 float* __restrict__ out) {
    int t = threadIdx.x;
    int l = t & 63;
    int w = t >> 6;
    int mtile = blockIdx.x * 4 + w;
    int m  = l & 15;
    int kg = l >> 4;
    int b  = mtile / kTilesPerB;
    int nn = (mtile - b * kTilesPerB) * 16 + m;
    const unsigned short* pb = poolb + (size_t)b * kNUp * kCin;
    const short8* wf = (const short8*)wfrag;

    f32x4 acc0 = {0.f, 0.f, 0.f, 0.f};
    f32x4 acc1 = {0.f, 0.f, 0.f, 0.f};

#pragma unroll 3
    for (int s = 0; s < kSeq; ++s) {
        int idx = indices[nn * kSeq + s];
        const short8* arow = (const short8*)(pb + (size_t)idx * kCin);
        short8 a0 = arow[kg];                        // k-chunk 2s   (channels 0..31)
        short8 a1 = arow[4 + kg];                    // k-chunk 2s+1 (channels 32..63)
        short8 b00 = wf[((s * 2 + 0) * 2 + 0) * 64 + l];
        short8 b01 = wf[((s * 2 + 0) * 2 + 1) * 64 + l];
        short8 b10 = wf[((s * 2 + 1) * 2 + 0) * 64 + l];
        short8 b11 = wf[((s * 2 + 1) * 2 + 1) * 64 + l];
        acc0 = __builtin_amdgcn_mfma_f32_16x16x32_bf16(a0, b00, acc0, 0, 0, 0);
        acc1 = __builtin_amdgcn_mfma_f32_16x16x32_bf16(a0, b01, acc1, 0, 0, 0);
        acc0 = __builtin_amdgcn_mfma_f32_16x16x32_bf16(a1, b10, acc0, 0, 0, 0);
        acc1 = __builtin_amdgcn_mfma_f32_16x16x32_bf16(a1, b11, acc1, 0, 0, 0);
    }

    float bs0 = bias[m];
    float bs1 = bias[16 + m];
    int orow0 = mtile * 16 + kg * 4;
#pragma unroll
    for (int r = 0; r < 4; ++r) {
        size_t orow = (size_t)(orow0 + r) * kCout;
        out[orow + m]      = fmaxf(acc0[r] + bs0, 0.f);
        out[orow + 16 + m] = fmaxf(acc1[r] + bs1, 0.f);
    }
}

extern "C" void kernel_launch(void* const* d_in, const int* in_sizes, int n_in,
                              void* d_out, int out_size, void* d_ws, size_t ws_size,
                              hipStream_t stream) {
    const float* x    = (const float*)d_in[0];
    const float* val  = (const float*)d_in[1];
    const float* W    = (const float*)d_in[2];
    const float* bias = (const float*)d_in[3];
    const int* row     = (const int*)d_in[4];
    const int* col     = (const int*)d_in[5];
    const int* indices = (const int*)d_in[6];
    float* out = (float*)d_out;

    char* wsb = (char*)d_ws;
    unsigned short* poolb = (unsigned short*)(wsb + kOffPool);
    unsigned short* wfrag = (unsigned short*)(wsb + kOffWfrag);
    int* cnt    = (int*)(wsb + kOffCnt);
    int* offs   = (int*)(wsb + kOffOffs);
    int* cursor = (int*)(wsb + kOffCur);
    uint2* elist = (uint2*)(wsb + kOffEl);

    hipMemsetAsync(cnt, 0, kNUp * sizeof(int), stream);
    hist_kernel<<<(kE + 255) / 256, 256, 0, stream>>>(row, cnt);
    scan_kernel<<<1, 1024, 0, stream>>>(cnt, offs, cursor);
    fill_kernel<<<(kE + 255) / 256, 256, 0, stream>>>(row, col, val, cursor, elist);
    pool_gather<<<kB * kNUp / 4, 256, 0, stream>>>(x, offs, cnt, elist, poolb);
    wprep_kernel<<<(kWFragN + 255) / 256, 256, 0, stream>>>(W, wfrag);
    gemm_mfma<<<(kMRows / 16) / 4, 256, 0, stream>>>(poolb, wfrag, bias, indices, out);
}

// Round 4
// 162.344 us; speedup vs baseline: 7.0953x; 1.2685x over previous
//
#include <hip/hip_runtime.h>
#include <hip/hip_bf16.h>

// SpiralDeblock: B=8, N_IN=7056, N_UP=28224, SEQ=9, CIN=64, COUT=32
namespace {
constexpr int kB    = 8;
constexpr int kNIn  = 7056;
constexpr int kNUp  = 28224;
constexpr int kSeq  = 9;
constexpr int kCin  = 64;
constexpr int kCout = 32;
constexpr int kE    = 3 * kNUp;          // 84672
constexpr int kMRows = kB * kNUp;        // 225792
constexpr int kTilesPerB = kNUp / 16;    // 1764 (exact -> tiles never straddle batches)
constexpr int kWFragN = 18 * 2 * 64 * 8; // 18432 bf16 values

// ws layout (bytes), all 16B-aligned
constexpr size_t kOffPool  = 0;                         // bf16 pooled: 8*28224*64*2 = 28,901,376
constexpr size_t kOffWfrag = 28901376;                  // 36,864
constexpr size_t kOffCnt   = kOffWfrag + 36864;         // 112,896
constexpr size_t kOffOffs  = kOffCnt + 112896;
constexpr size_t kOffCur   = kOffOffs + 112896;
constexpr size_t kOffEl    = kOffCur + 112896;          // E*8 = 677,376  (total ~30 MB)
}

typedef __attribute__((ext_vector_type(8))) short short8;
typedef __attribute__((ext_vector_type(4))) float f32x4;

__device__ __forceinline__ unsigned short f32_to_bf16(float f) {  // RNE
    unsigned int u = __float_as_uint(f);
    u += 0x7fffu + ((u >> 16) & 1u);
    return (unsigned short)(u >> 16);
}

// --- CSR build: invert row[] ---------------------------------------------
__global__ void hist_kernel(const int* __restrict__ row, int* __restrict__ cnt) {
    int e = blockIdx.x * 256 + threadIdx.x;
    if (e < kE) atomicAdd(&cnt[row[e]], 1);
}

// single block, 1024 threads: exclusive prefix sum of cnt -> offs, cursor
__global__ __launch_bounds__(1024) void scan_kernel(const int* __restrict__ cnt,
                                                    int* __restrict__ offs,
                                                    int* __restrict__ cursor) {
    __shared__ int part[1024];
    int t = threadIdx.x;
    int lo = t * 28, hi = min(lo + 28, kNUp);
    int s = 0;
    for (int i = lo; i < hi; ++i) s += cnt[i];
    part[t] = s;
    __syncthreads();
    for (int off = 1; off < 1024; off <<= 1) {
        int v = (t >= off) ? part[t - off] : 0;
        __syncthreads();
        part[t] += v;
        __syncthreads();
    }
    int base = (t == 0) ? 0 : part[t - 1];
    for (int i = lo; i < hi; ++i) {
        offs[i] = base;
        cursor[i] = base;
        base += cnt[i];
    }
}

__global__ void fill_kernel(const int* __restrict__ row, const int* __restrict__ col,
                            const float* __restrict__ val, int* __restrict__ cursor,
                            uint2* __restrict__ elist) {
    int e = blockIdx.x * 256 + threadIdx.x;
    if (e >= kE) return;
    int r = row[e];
    int slot = atomicAdd(&cursor[r], 1);
    elist[slot] = make_uint2((unsigned)col[e], __float_as_uint(val[e]));
}

// --- pooled[b,r,c] = sum_{e in CSR[r]} x[b,col[e],c]*val[e], stored bf16 ---
// thread = (r, c), accumulates ALL 8 batches: 8 independent loads per edge (ILP),
// elist/offs/cnt reads amortized 8x. block = 4 rows x 64 channels.
__global__ __launch_bounds__(256) void pool_gather(const float* __restrict__ x,
                                                   const int* __restrict__ offs,
                                                   const int* __restrict__ cnt,
                                                   const uint2* __restrict__ elist,
                                                   unsigned short* __restrict__ poolb) {
    int t = threadIdx.x;
    int c = t & 63;
    int r = blockIdx.x * 4 + (t >> 6);               // < N_UP
    int e0 = offs[r], n = cnt[r];
    float acc[kB] = {0.f, 0.f, 0.f, 0.f, 0.f, 0.f, 0.f, 0.f};
    for (int k = 0; k < n; ++k) {
        uint2 ev = elist[e0 + k];                    // broadcast across the wave
        float v = __uint_as_float(ev.y);
        const float* xp = x + (size_t)ev.x * kCin + c;
#pragma unroll
        for (int b = 0; b < kB; ++b)
            acc[b] = fmaf(xp[(size_t)b * kNIn * kCin], v, acc[b]);
    }
#pragma unroll
    for (int b = 0; b < kB; ++b)
        poolb[((size_t)b * kNUp + r) * kCin + c] = f32_to_bf16(acc[b]);
}

// --- W -> MFMA B-fragment order, bf16 ------------------------------------
// frag value (ks, ct, lane l, j) = W[ks*32 + (l>>4)*8 + j][ct*16 + (l&15)]
__global__ void wprep_kernel(const float* __restrict__ W, unsigned short* __restrict__ wfrag) {
    int i = blockIdx.x * 256 + threadIdx.x;
    if (i >= kWFragN) return;
    int j  = i & 7;
    int l  = (i >> 3) & 63;
    int ct = (i >> 9) & 1;
    int ks = i >> 10;                                // 0..17
    int k  = ks * 32 + (l >> 4) * 8 + j;
    int o  = ct * 16 + (l & 15);
    wfrag[i] = f32_to_bf16(W[k * kCout + o]);
}

// --- MFMA GEMM: out[R,o] = relu(sum_f spiral[R,f]*W[f,o] + bias[o]) -------
// 4 waves/block, 1 16-row M-tile per wave, both 16-col tiles; K=576 in 18 chunks of 32.
// All 9 idx loads hoisted, all 18 A-fragments prefetched (72 VGPR), then 36 MFMA.
// XCD chunk swizzle: 441 consecutive work-ids = one batch (3.6 MB pooled slice < 4 MiB L2/XCD).
__global__ __launch_bounds__(256) void gemm_mfma(const unsigned short* __restrict__ poolb,
                                                 const unsigned short* __restrict__ wfrag,
                                                 const float* __restrict__ bias,
                                                 const int* __restrict__ indices,
                                                 float* __restrict__ out) {
    int t = threadIdx.x;
    int l = t & 63;
    int w = t >> 6;
    int bid = blockIdx.x;
    int wk = (bid & 7) * (gridDim.x >> 3) + (bid >> 3);  // grid 3528 = 8*441
    int mtile = wk * 4 + w;
    int m  = l & 15;
    int kg = l >> 4;
    int b  = mtile / kTilesPerB;
    int nn = (mtile - b * kTilesPerB) * 16 + m;
    const unsigned short* pb = poolb + (size_t)b * kNUp * kCin;
    const short8* wf = (const short8*)wfrag;

    int idxs[kSeq];
#pragma unroll
    for (int s = 0; s < kSeq; ++s) idxs[s] = indices[nn * kSeq + s];

    short8 A0[kSeq], A1[kSeq];
#pragma unroll
    for (int s = 0; s < kSeq; ++s) {
        const short8* arow = (const short8*)(pb + (size_t)idxs[s] * kCin);
        A0[s] = arow[kg];                            // channels 0..31, this lane's 16B
        A1[s] = arow[4 + kg];                        // channels 32..63
    }

    f32x4 acc0 = {0.f, 0.f, 0.f, 0.f};
    f32x4 acc1 = {0.f, 0.f, 0.f, 0.f};
#pragma unroll
    for (int s = 0; s < kSeq; ++s) {
        short8 b00 = wf[((s * 2 + 0) * 2 + 0) * 64 + l];
        short8 b01 = wf[((s * 2 + 0) * 2 + 1) * 64 + l];
        short8 b10 = wf[((s * 2 + 1) * 2 + 0) * 64 + l];
        short8 b11 = wf[((s * 2 + 1) * 2 + 1) * 64 + l];
        acc0 = __builtin_amdgcn_mfma_f32_16x16x32_bf16(A0[s], b00, acc0, 0, 0, 0);
        acc1 = __builtin_amdgcn_mfma_f32_16x16x32_bf16(A0[s], b01, acc1, 0, 0, 0);
        acc0 = __builtin_amdgcn_mfma_f32_16x16x32_bf16(A1[s], b10, acc0, 0, 0, 0);
        acc1 = __builtin_amdgcn_mfma_f32_16x16x32_bf16(A1[s], b11, acc1, 0, 0, 0);
    }

    float bs0 = bias[m];
    float bs1 = bias[16 + m];
    int orow0 = mtile * 16 + kg * 4;
#pragma unroll
    for (int r = 0; r < 4; ++r) {
        size_t orow = (size_t)(orow0 + r) * kCout;
        out[orow + m]      = fmaxf(acc0[r] + bs0, 0.f);
        out[orow + 16 + m] = fmaxf(acc1[r] + bs1, 0.f);
    }
}

extern "C" void kernel_launch(void* const* d_in, const int* in_sizes, int n_in,
                              void* d_out, int out_size, void* d_ws, size_t ws_size,
                              hipStream_t stream) {
    const float* x    = (const float*)d_in[0];
    const float* val  = (const float*)d_in[1];
    const float* W    = (const float*)d_in[2];
    const float* bias = (const float*)d_in[3];
    const int* row     = (const int*)d_in[4];
    const int* col     = (const int*)d_in[5];
    const int* indices = (const int*)d_in[6];
    float* out = (float*)d_out;

    char* wsb = (char*)d_ws;
    unsigned short* poolb = (unsigned short*)(wsb + kOffPool);
    unsigned short* wfrag = (unsigned short*)(wsb + kOffWfrag);
    int* cnt    = (int*)(wsb + kOffCnt);
    int* offs   = (int*)(wsb + kOffOffs);
    int* cursor = (int*)(wsb + kOffCur);
    uint2* elist = (uint2*)(wsb + kOffEl);

    hipMemsetAsync(cnt, 0, kNUp * sizeof(int), stream);
    hist_kernel<<<(kE + 255) / 256, 256, 0, stream>>>(row, cnt);
    scan_kernel<<<1, 1024, 0, stream>>>(cnt, offs, cursor);
    fill_kernel<<<(kE + 255) / 256, 256, 0, stream>>>(row, col, val, cursor, elist);
    pool_gather<<<kNUp / 4, 256, 0, stream>>>(x, offs, cnt, elist, poolb);
    wprep_kernel<<<(kWFragN + 255) / 256, 256, 0, stream>>>(W, wfrag);
    gemm_mfma<<<(kMRows / 16) / 4, 256, 0, stream>>>(poolb, wfrag, bias, indices, out);
}

// Round 5
// 100.565 us; speedup vs baseline: 11.4540x; 1.6143x over previous
//
#include <hip/hip_runtime.h>
#include <hip/hip_bf16.h>

// SpiralDeblock: B=8, N_IN=7056, N_UP=28224, SEQ=9, CIN=64, COUT=32
namespace {
constexpr int kB    = 8;
constexpr int kNIn  = 7056;
constexpr int kNUp  = 28224;
constexpr int kSeq  = 9;
constexpr int kCin  = 64;
constexpr int kCout = 32;
constexpr int kE    = 3 * kNUp;          // 84672
constexpr int kMRows = kB * kNUp;        // 225792
constexpr int kTilesPerB = kNUp / 16;    // 1764 (exact -> tiles never straddle batches)
constexpr int kWFragN = 18 * 2 * 64 * 8; // 18432 bf16 values
constexpr int kCap   = 24;               // bucket capacity; P(overflow) ~ 6e-10 at Poisson(3)

// ws layout (bytes), 16B-aligned; round-2 proved ws_size >= 57.8 MB, this uses 34.5 MB
constexpr size_t kOffPool   = 0;                          // bf16 pooled: 28,901,376
constexpr size_t kOffWfrag  = 28901376;                   // 36,864
constexpr size_t kOffCur    = kOffWfrag + 36864;          // 112,896
constexpr size_t kOffBucket = kOffCur + 112896;           // N_UP*24*8 = 5,419,008
}

typedef __attribute__((ext_vector_type(8))) short short8;
typedef __attribute__((ext_vector_type(4))) float f32x4;

__device__ __forceinline__ unsigned short f32_to_bf16(float f) {  // RNE
    unsigned int u = __float_as_uint(f);
    u += 0x7fffu + ((u >> 16) & 1u);
    return (unsigned short)(u >> 16);
}

// --- merged prep: blocks [0,72) transpose W to fragment order; blocks [72,...) bucket edges
// W frag value (ks, ct, lane l, j) = W[ks*32 + (l>>4)*8 + j][ct*16 + (l&15)]
__global__ __launch_bounds__(256) void prep_kernel(const float* __restrict__ W,
                                                   unsigned short* __restrict__ wfrag,
                                                   const int* __restrict__ row,
                                                   const int* __restrict__ col,
                                                   const float* __restrict__ val,
                                                   int* __restrict__ cursor,
                                                   uint2* __restrict__ bucket) {
    int bid = blockIdx.x;
    if (bid < kWFragN / 256) {
        int i  = bid * 256 + threadIdx.x;
        int j  = i & 7;
        int l  = (i >> 3) & 63;
        int ct = (i >> 9) & 1;
        int ks = i >> 10;                            // 0..17
        int k  = ks * 32 + (l >> 4) * 8 + j;
        int o  = ct * 16 + (l & 15);
        wfrag[i] = f32_to_bf16(W[k * kCout + o]);
    } else {
        int e = (bid - kWFragN / 256) * 256 + threadIdx.x;
        if (e >= kE) return;
        int r = row[e];
        int slot = atomicAdd(&cursor[r], 1);
        if (slot < kCap)
            bucket[(size_t)r * kCap + slot] = make_uint2((unsigned)col[e], __float_as_uint(val[e]));
    }
}

// --- pooled[b,r,c] = sum_{edges of r} x[b,col,c]*val, stored bf16 ---------
// thread = (r, c), accumulates ALL 8 batches: 8 independent loads per edge (ILP 8),
// bucket reads amortized 8x. block = 4 rows x 64 channels.
__global__ __launch_bounds__(256) void pool_gather(const float* __restrict__ x,
                                                   const int* __restrict__ cursor,
                                                   const uint2* __restrict__ bucket,
                                                   unsigned short* __restrict__ poolb) {
    int t = threadIdx.x;
    int c = t & 63;
    int r = blockIdx.x * 4 + (t >> 6);               // < N_UP
    int n = min(cursor[r], kCap);
    const uint2* bk = bucket + (size_t)r * kCap;
    float acc[kB] = {0.f, 0.f, 0.f, 0.f, 0.f, 0.f, 0.f, 0.f};
    for (int k = 0; k < n; ++k) {
        uint2 ev = bk[k];                            // broadcast across the wave
        float v = __uint_as_float(ev.y);
        const float* xp = x + (size_t)ev.x * kCin + c;
#pragma unroll
        for (int b = 0; b < kB; ++b)
            acc[b] = fmaf(xp[(size_t)b * kNIn * kCin], v, acc[b]);
    }
#pragma unroll
    for (int b = 0; b < kB; ++b)
        poolb[((size_t)b * kNUp + r) * kCin + c] = f32_to_bf16(acc[b]);
}

// --- MFMA GEMM: out[R,o] = relu(sum_f spiral[R,f]*W[f,o] + bias[o]) -------
// 4 waves/block, 1 16-row M-tile per wave, both 16-col tiles; K=576 in 18 chunks of 32.
// All 9 idx loads hoisted, all 18 A-fragments prefetched, then 36 MFMA.
// XCD chunk swizzle: 441 consecutive work-ids = one batch (3.6 MB pooled slice < 4 MiB L2/XCD).
__global__ __launch_bounds__(256) void gemm_mfma(const unsigned short* __restrict__ poolb,
                                                 const unsigned short* __restrict__ wfrag,
                                                 const float* __restrict__ bias,
                                                 const int* __restrict__ indices,
                                                 float* __restrict__ out) {
    int t = threadIdx.x;
    int l = t & 63;
    int w = t >> 6;
    int bid = blockIdx.x;
    int wk = (bid & 7) * (gridDim.x >> 3) + (bid >> 3);  // grid 3528 = 8*441
    int mtile = wk * 4 + w;
    int m  = l & 15;
    int kg = l >> 4;
    int b  = mtile / kTilesPerB;
    int nn = (mtile - b * kTilesPerB) * 16 + m;
    const unsigned short* pb = poolb + (size_t)b * kNUp * kCin;
    const short8* wf = (const short8*)wfrag;

    int idxs[kSeq];
#pragma unroll
    for (int s = 0; s < kSeq; ++s) idxs[s] = indices[nn * kSeq + s];

    short8 A0[kSeq], A1[kSeq];
#pragma unroll
    for (int s = 0; s < kSeq; ++s) {
        const short8* arow = (const short8*)(pb + (size_t)idxs[s] * kCin);
        A0[s] = arow[kg];                            // channels 0..31, this lane's 16B
        A1[s] = arow[4 + kg];                        // channels 32..63
    }

    f32x4 acc0 = {0.f, 0.f, 0.f, 0.f};
    f32x4 acc1 = {0.f, 0.f, 0.f, 0.f};
#pragma unroll
    for (int s = 0; s < kSeq; ++s) {
        short8 b00 = wf[((s * 2 + 0) * 2 + 0) * 64 + l];
        short8 b01 = wf[((s * 2 + 0) * 2 + 1) * 64 + l];
        short8 b10 = wf[((s * 2 + 1) * 2 + 0) * 64 + l];
        short8 b11 = wf[((s * 2 + 1) * 2 + 1) * 64 + l];
        acc0 = __builtin_amdgcn_mfma_f32_16x16x32_bf16(A0[s], b00, acc0, 0, 0, 0);
        acc1 = __builtin_amdgcn_mfma_f32_16x16x32_bf16(A0[s], b01, acc1, 0, 0, 0);
        acc0 = __builtin_amdgcn_mfma_f32_16x16x32_bf16(A1[s], b10, acc0, 0, 0, 0);
        acc1 = __builtin_amdgcn_mfma_f32_16x16x32_bf16(A1[s], b11, acc1, 0, 0, 0);
    }

    float bs0 = bias[m];
    float bs1 = bias[16 + m];
    int orow0 = mtile * 16 + kg * 4;
#pragma unroll
    for (int r = 0; r < 4; ++r) {
        size_t orow = (size_t)(orow0 + r) * kCout;
        out[orow + m]      = fmaxf(acc0[r] + bs0, 0.f);
        out[orow + 16 + m] = fmaxf(acc1[r] + bs1, 0.f);
    }
}

extern "C" void kernel_launch(void* const* d_in, const int* in_sizes, int n_in,
                              void* d_out, int out_size, void* d_ws, size_t ws_size,
                              hipStream_t stream) {
    const float* x    = (const float*)d_in[0];
    const float* val  = (const float*)d_in[1];
    const float* W    = (const float*)d_in[2];
    const float* bias = (const float*)d_in[3];
    const int* row     = (const int*)d_in[4];
    const int* col     = (const int*)d_in[5];
    const int* indices = (const int*)d_in[6];
    float* out = (float*)d_out;

    char* wsb = (char*)d_ws;
    unsigned short* poolb = (unsigned short*)(wsb + kOffPool);
    unsigned short* wfrag = (unsigned short*)(wsb + kOffWfrag);
    int* cursor  = (int*)(wsb + kOffCur);
    uint2* bucket = (uint2*)(wsb + kOffBucket);

    hipMemsetAsync(cursor, 0, kNUp * sizeof(int), stream);

    constexpr int prep_blocks = kWFragN / 256 + (kE + 255) / 256;  // 72 + 331
    prep_kernel<<<prep_blocks, 256, 0, stream>>>(W, wfrag, row, col, val, cursor, bucket);

    pool_gather<<<kNUp / 4, 256, 0, stream>>>(x, cursor, bucket, poolb);

    gemm_mfma<<<(kMRows / 16) / 4, 256, 0, stream>>>(poolb, wfrag, bias, indices, out);
}

// Round 6
// 81.280 us; speedup vs baseline: 14.1717x; 1.2373x over previous
//
#include <hip/hip_runtime.h>
#include <hip/hip_bf16.h>

// SpiralDeblock: B=8, N_IN=7056, N_UP=28224, SEQ=9, CIN=64, COUT=32
namespace {
constexpr int kB    = 8;
constexpr int kNIn  = 7056;
constexpr int kNUp  = 28224;
constexpr int kSeq  = 9;
constexpr int kCin  = 64;
constexpr int kCout = 32;
constexpr int kE    = 3 * kNUp;          // 84672
constexpr int kMRows = kB * kNUp;        // 225792
constexpr int kTilesPerB = kNUp / 16;    // 1764 (exact -> tiles never straddle batches)
constexpr int kWFragN = 18 * 2 * 64 * 8; // 18432 bf16 values (36,864 B)
constexpr int kCap   = 24;               // bucket capacity; P(overflow) ~ 6e-10 at Poisson(3)

// ws layout (bytes), 16B-aligned
constexpr size_t kOffPool   = 0;                          // bf16 pooled: 28,901,376
constexpr size_t kOffWfrag  = 28901376;                   // 36,864
constexpr size_t kOffCur    = kOffWfrag + 36864;          // 112,896
constexpr size_t kOffBucket = kOffCur + 112896;           // N_UP*24*8 = 5,419,008
}

typedef __attribute__((ext_vector_type(8))) short short8;
typedef __attribute__((ext_vector_type(4))) float f32x4;

__device__ __forceinline__ unsigned short f32_to_bf16(float f) {  // RNE
    unsigned int u = __float_as_uint(f);
    u += 0x7fffu + ((u >> 16) & 1u);
    return (unsigned short)(u >> 16);
}

// --- merged prep: blocks [0,72) transpose W to fragment order; blocks [72,...) bucket edges
__global__ __launch_bounds__(256) void prep_kernel(const float* __restrict__ W,
                                                   unsigned short* __restrict__ wfrag,
                                                   const int* __restrict__ row,
                                                   const int* __restrict__ col,
                                                   const float* __restrict__ val,
                                                   int* __restrict__ cursor,
                                                   uint2* __restrict__ bucket) {
    int bid = blockIdx.x;
    if (bid < kWFragN / 256) {
        int i  = bid * 256 + threadIdx.x;
        int j  = i & 7;
        int l  = (i >> 3) & 63;
        int ct = (i >> 9) & 1;
        int ks = i >> 10;                            // 0..17
        int k  = ks * 32 + (l >> 4) * 8 + j;
        int o  = ct * 16 + (l & 15);
        wfrag[i] = f32_to_bf16(W[k * kCout + o]);
    } else {
        int e = (bid - kWFragN / 256) * 256 + threadIdx.x;
        if (e >= kE) return;
        int r = row[e];
        int slot = atomicAdd(&cursor[r], 1);
        if (slot < kCap)
            bucket[(size_t)r * kCap + slot] = make_uint2((unsigned)col[e], __float_as_uint(val[e]));
    }
}

// --- pooled[b,r,c] = sum_{edges of r} x[b,col,c]*val, stored bf16 ---------
// wave = one row r (c spans 64 lanes). Edges processed in PAIRS: bucket pair
// prefetched as uint4, 16 independent x-loads in flight; predicate (v=0, col
// clamped) handles odd n / garbage slots. Wave-uniform branches on n.
__global__ __launch_bounds__(256) void pool_gather(const float* __restrict__ x,
                                                   const int* __restrict__ cursor,
                                                   const uint2* __restrict__ bucket,
                                                   unsigned short* __restrict__ poolb) {
    int t = threadIdx.x;
    int c = t & 63;
    int r = blockIdx.x * 4 + (t >> 6);               // < N_UP
    int n = min(cursor[r], kCap);
    const uint2* bk = bucket + (size_t)r * kCap;
    float acc[kB] = {0.f, 0.f, 0.f, 0.f, 0.f, 0.f, 0.f, 0.f};

#pragma unroll
    for (int p = 0; p < 4; ++p) {                    // pairs (0,1),(2,3),(4,5),(6,7)
        if (2 * p < n) {
            uint4 q = *reinterpret_cast<const uint4*>(bk + 2 * p);
            unsigned c0 = min(q.x, (unsigned)(kNIn - 1));
            float    v0 = __uint_as_float(q.y);
            unsigned c1 = min(q.z, (unsigned)(kNIn - 1));
            float    v1 = (2 * p + 1 < n) ? __uint_as_float(q.w) : 0.f;
            const float* x0 = x + (size_t)c0 * kCin + c;
            const float* x1 = x + (size_t)c1 * kCin + c;
            float xv0[kB], xv1[kB];
#pragma unroll
            for (int b = 0; b < kB; ++b) {           // 16 independent loads
                xv0[b] = x0[(size_t)b * kNIn * kCin];
                xv1[b] = x1[(size_t)b * kNIn * kCin];
            }
#pragma unroll
            for (int b = 0; b < kB; ++b)
                acc[b] = fmaf(xv1[b], v1, fmaf(xv0[b], v0, acc[b]));
        }
    }
    for (int k = 8; k < n; ++k) {                    // rare tail (P ~ 0.4%)
        uint2 ev = bk[k];
        float v = __uint_as_float(ev.y);
        const float* xp = x + (size_t)ev.x * kCin + c;
#pragma unroll
        for (int b = 0; b < kB; ++b)
            acc[b] = fmaf(xp[(size_t)b * kNIn * kCin], v, acc[b]);
    }
#pragma unroll
    for (int b = 0; b < kB; ++b)
        poolb[((size_t)b * kNUp + r) * kCin + c] = f32_to_bf16(acc[b]);
}

// --- MFMA GEMM: out[R,o] = relu(sum_f spiral[R,f]*W[f,o] + bias[o]) -------
// 4 waves/block, 1 16-row M-tile per wave. W fragments staged in LDS (36,864 B,
// 4 blocks/CU) -- kills the per-wave 36KB global B-stream (L1 thrash). All 9 idx
// + 18 A-fragment loads issued BEFORE __syncthreads(): barrier fence keeps them
// hoisted, its vmcnt-drain hides their latency under the LDS fill.
// XCD chunk swizzle: 441 consecutive work-ids = one batch (3.6 MB < 4 MiB L2/XCD).
__global__ __launch_bounds__(256) void gemm_mfma(const unsigned short* __restrict__ poolb,
                                                 const unsigned short* __restrict__ wfrag,
                                                 const float* __restrict__ bias,
                                                 const int* __restrict__ indices,
                                                 float* __restrict__ out) {
    __shared__ short8 Bs[18 * 2 * 64];               // 2304 short8 = 36,864 B
    int t = threadIdx.x;
    const short8* wf = (const short8*)wfrag;
#pragma unroll
    for (int i = 0; i < 9; ++i)                      // coalesced b128 fill
        Bs[i * 256 + t] = wf[i * 256 + t];

    int l = t & 63;
    int w = t >> 6;
    int bid = blockIdx.x;
    int wk = (bid & 7) * (gridDim.x >> 3) + (bid >> 3);  // grid 3528 = 8*441
    int mtile = wk * 4 + w;
    int m  = l & 15;
    int kg = l >> 4;
    int b  = mtile / kTilesPerB;
    int nn = (mtile - b * kTilesPerB) * 16 + m;
    const unsigned short* pb = poolb + (size_t)b * kNUp * kCin;

    int idxs[kSeq];
#pragma unroll
    for (int s = 0; s < kSeq; ++s) idxs[s] = indices[nn * kSeq + s];

    short8 A0[kSeq], A1[kSeq];
#pragma unroll
    for (int s = 0; s < kSeq; ++s) {
        const short8* arow = (const short8*)(pb + (size_t)idxs[s] * kCin);
        A0[s] = arow[kg];                            // channels 0..31, this lane's 16B
        A1[s] = arow[4 + kg];                        // channels 32..63
    }
    float bs0 = bias[m];
    float bs1 = bias[16 + m];

    __syncthreads();                                 // Bs ready; A loads drained here

    f32x4 acc0 = {0.f, 0.f, 0.f, 0.f};
    f32x4 acc1 = {0.f, 0.f, 0.f, 0.f};
#pragma unroll
    for (int s = 0; s < kSeq; ++s) {
        short8 b00 = Bs[((s * 2 + 0) * 2 + 0) * 64 + l];
        short8 b01 = Bs[((s * 2 + 0) * 2 + 1) * 64 + l];
        short8 b10 = Bs[((s * 2 + 1) * 2 + 0) * 64 + l];
        short8 b11 = Bs[((s * 2 + 1) * 2 + 1) * 64 + l];
        acc0 = __builtin_amdgcn_mfma_f32_16x16x32_bf16(A0[s], b00, acc0, 0, 0, 0);
        acc1 = __builtin_amdgcn_mfma_f32_16x16x32_bf16(A0[s], b01, acc1, 0, 0, 0);
        acc0 = __builtin_amdgcn_mfma_f32_16x16x32_bf16(A1[s], b10, acc0, 0, 0, 0);
        acc1 = __builtin_amdgcn_mfma_f32_16x16x32_bf16(A1[s], b11, acc1, 0, 0, 0);
    }

    int orow0 = mtile * 16 + kg * 4;
#pragma unroll
    for (int r = 0; r < 4; ++r) {
        size_t orow = (size_t)(orow0 + r) * kCout;
        out[orow + m]      = fmaxf(acc0[r] + bs0, 0.f);
        out[orow + 16 + m] = fmaxf(acc1[r] + bs1, 0.f);
    }
}

extern "C" void kernel_launch(void* const* d_in, const int* in_sizes, int n_in,
                              void* d_out, int out_size, void* d_ws, size_t ws_size,
                              hipStream_t stream) {
    const float* x    = (const float*)d_in[0];
    const float* val  = (const float*)d_in[1];
    const float* W    = (const float*)d_in[2];
    const float* bias = (const float*)d_in[3];
    const int* row     = (const int*)d_in[4];
    const int* col     = (const int*)d_in[5];
    const int* indices = (const int*)d_in[6];
    float* out = (float*)d_out;

    char* wsb = (char*)d_ws;
    unsigned short* poolb = (unsigned short*)(wsb + kOffPool);
    unsigned short* wfrag = (unsigned short*)(wsb + kOffWfrag);
    int* cursor  = (int*)(wsb + kOffCur);
    uint2* bucket = (uint2*)(wsb + kOffBucket);

    hipMemsetAsync(cursor, 0, kNUp * sizeof(int), stream);

    constexpr int prep_blocks = kWFragN / 256 + (kE + 255) / 256;  // 72 + 331
    prep_kernel<<<prep_blocks, 256, 0, stream>>>(W, wfrag, row, col, val, cursor, bucket);

    pool_gather<<<kNUp / 4, 256, 0, stream>>>(x, cursor, bucket, poolb);

    gemm_mfma<<<(kMRows / 16) / 4, 256, 0, stream>>>(poolb, wfrag, bias, indices, out);
}

// Round 7
// 81.248 us; speedup vs baseline: 14.1773x; 1.0004x over previous
//
#include <hip/hip_runtime.h>
#include <hip/hip_bf16.h>

// SpiralDeblock: B=8, N_IN=7056, N_UP=28224, SEQ=9, CIN=64, COUT=32
namespace {
constexpr int kB    = 8;
constexpr int kNIn  = 7056;
constexpr int kNUp  = 28224;
constexpr int kSeq  = 9;
constexpr int kCin  = 64;
constexpr int kCout = 32;
constexpr int kE    = 3 * kNUp;          // 84672
constexpr int kMRows = kB * kNUp;        // 225792
constexpr int kTilesPerB = kNUp / 16;    // 1764 (exact -> tiles never straddle batches)
constexpr int kWFragN = 18 * 2 * 64 * 8; // 18432 bf16 values (36,864 B)
constexpr int kCap   = 24;               // bucket capacity; P(overflow) ~ 6e-10 at Poisson(3)

// ws layout (bytes), 16B-aligned
constexpr size_t kOffPool   = 0;                          // bf16 pooled: 28,901,376
constexpr size_t kOffWfrag  = 28901376;                   // 36,864
constexpr size_t kOffCur    = kOffWfrag + 36864;          // 112,896
constexpr size_t kOffBucket = kOffCur + 112896;           // N_UP*24*8 = 5,419,008
}

typedef __attribute__((ext_vector_type(8))) short short8;
typedef __attribute__((ext_vector_type(4))) float f32x4;

__device__ __forceinline__ unsigned short f32_to_bf16(float f) {  // RNE
    unsigned int u = __float_as_uint(f);
    u += 0x7fffu + ((u >> 16) & 1u);
    return (unsigned short)(u >> 16);
}

// --- zero cursor: replaces hipMemsetAsync, whose rocclr fill kernel measured
// 48 us (!) for 113 KB in-graph. 111 blocks of coalesced dword stores ~2-3 us.
__global__ __launch_bounds__(256) void zero_kernel(int* __restrict__ cursor) {
    int i = blockIdx.x * 256 + threadIdx.x;
    if (i < kNUp) cursor[i] = 0;
}

// --- merged prep: blocks [0,72) transpose W to fragment order; blocks [72,...) bucket edges
__global__ __launch_bounds__(256) void prep_kernel(const float* __restrict__ W,
                                                   unsigned short* __restrict__ wfrag,
                                                   const int* __restrict__ row,
                                                   const int* __restrict__ col,
                                                   const float* __restrict__ val,
                                                   int* __restrict__ cursor,
                                                   uint2* __restrict__ bucket) {
    int bid = blockIdx.x;
    if (bid < kWFragN / 256) {
        int i  = bid * 256 + threadIdx.x;
        int j  = i & 7;
        int l  = (i >> 3) & 63;
        int ct = (i >> 9) & 1;
        int ks = i >> 10;                            // 0..17
        int k  = ks * 32 + (l >> 4) * 8 + j;
        int o  = ct * 16 + (l & 15);
        wfrag[i] = f32_to_bf16(W[k * kCout + o]);
    } else {
        int e = (bid - kWFragN / 256) * 256 + threadIdx.x;
        if (e >= kE) return;
        int r = row[e];
        int slot = atomicAdd(&cursor[r], 1);
        if ((unsigned)slot < (unsigned)kCap)
            bucket[(size_t)r * kCap + slot] = make_uint2((unsigned)col[e], __float_as_uint(val[e]));
    }
}

// --- pooled[b,r,c] = sum_{edges of r} x[b,col,c]*val, stored bf16 ---------
// wave = one row r (c spans 64 lanes). Edges processed in PAIRS: bucket pair
// prefetched as uint4, 16 independent x-loads in flight; predicate (v=0, col
// clamped) handles odd n / garbage slots. Wave-uniform branches on n.
__global__ __launch_bounds__(256) void pool_gather(const float* __restrict__ x,
                                                   const int* __restrict__ cursor,
                                                   const uint2* __restrict__ bucket,
                                                   unsigned short* __restrict__ poolb) {
    int t = threadIdx.x;
    int c = t & 63;
    int r = blockIdx.x * 4 + (t >> 6);               // < N_UP
    int n = min(cursor[r], kCap);
    const uint2* bk = bucket + (size_t)r * kCap;
    float acc[kB] = {0.f, 0.f, 0.f, 0.f, 0.f, 0.f, 0.f, 0.f};

#pragma unroll
    for (int p = 0; p < 4; ++p) {                    // pairs (0,1),(2,3),(4,5),(6,7)
        if (2 * p < n) {
            uint4 q = *reinterpret_cast<const uint4*>(bk + 2 * p);
            unsigned c0 = min(q.x, (unsigned)(kNIn - 1));
            float    v0 = __uint_as_float(q.y);
            unsigned c1 = min(q.z, (unsigned)(kNIn - 1));
            float    v1 = (2 * p + 1 < n) ? __uint_as_float(q.w) : 0.f;
            const float* x0 = x + (size_t)c0 * kCin + c;
            const float* x1 = x + (size_t)c1 * kCin + c;
            float xv0[kB], xv1[kB];
#pragma unroll
            for (int b = 0; b < kB; ++b) {           // 16 independent loads
                xv0[b] = x0[(size_t)b * kNIn * kCin];
                xv1[b] = x1[(size_t)b * kNIn * kCin];
            }
#pragma unroll
            for (int b = 0; b < kB; ++b)
                acc[b] = fmaf(xv1[b], v1, fmaf(xv0[b], v0, acc[b]));
        }
    }
    for (int k = 8; k < n; ++k) {                    // rare tail (P ~ 0.4%)
        uint2 ev = bk[k];
        float v = __uint_as_float(ev.y);
        const float* xp = x + (size_t)ev.x * kCin + c;
#pragma unroll
        for (int b = 0; b < kB; ++b)
            acc[b] = fmaf(xp[(size_t)b * kNIn * kCin], v, acc[b]);
    }
#pragma unroll
    for (int b = 0; b < kB; ++b)
        poolb[((size_t)b * kNUp + r) * kCin + c] = f32_to_bf16(acc[b]);
}

// --- MFMA GEMM: out[R,o] = relu(sum_f spiral[R,f]*W[f,o] + bias[o]) -------
// 4 waves/block, 1 16-row M-tile per wave. W fragments staged in LDS (36,864 B,
// 4 blocks/CU). All 9 idx + 18 A-fragment loads issued BEFORE __syncthreads():
// barrier fence keeps them hoisted, vmcnt-drain hides latency under LDS fill.
// XCD chunk swizzle: 441 consecutive work-ids = one batch (3.6 MB < 4 MiB L2/XCD).
__global__ __launch_bounds__(256) void gemm_mfma(const unsigned short* __restrict__ poolb,
                                                 const unsigned short* __restrict__ wfrag,
                                                 const float* __restrict__ bias,
                                                 const int* __restrict__ indices,
                                                 float* __restrict__ out) {
    __shared__ short8 Bs[18 * 2 * 64];               // 2304 short8 = 36,864 B
    int t = threadIdx.x;
    const short8* wf = (const short8*)wfrag;
#pragma unroll
    for (int i = 0; i < 9; ++i)                      // coalesced b128 fill
        Bs[i * 256 + t] = wf[i * 256 + t];

    int l = t & 63;
    int w = t >> 6;
    int bid = blockIdx.x;
    int wk = (bid & 7) * (gridDim.x >> 3) + (bid >> 3);  // grid 3528 = 8*441
    int mtile = wk * 4 + w;
    int m  = l & 15;
    int kg = l >> 4;
    int b  = mtile / kTilesPerB;
    int nn = (mtile - b * kTilesPerB) * 16 + m;
    const unsigned short* pb = poolb + (size_t)b * kNUp * kCin;

    int idxs[kSeq];
#pragma unroll
    for (int s = 0; s < kSeq; ++s) idxs[s] = indices[nn * kSeq + s];

    short8 A0[kSeq], A1[kSeq];
#pragma unroll
    for (int s = 0; s < kSeq; ++s) {
        const short8* arow = (const short8*)(pb + (size_t)idxs[s] * kCin);
        A0[s] = arow[kg];                            // channels 0..31, this lane's 16B
        A1[s] = arow[4 + kg];                        // channels 32..63
    }
    float bs0 = bias[m];
    float bs1 = bias[16 + m];

    __syncthreads();                                 // Bs ready; A loads drained here

    f32x4 acc0 = {0.f, 0.f, 0.f, 0.f};
    f32x4 acc1 = {0.f, 0.f, 0.f, 0.f};
#pragma unroll
    for (int s = 0; s < kSeq; ++s) {
        short8 b00 = Bs[((s * 2 + 0) * 2 + 0) * 64 + l];
        short8 b01 = Bs[((s * 2 + 0) * 2 + 1) * 64 + l];
        short8 b10 = Bs[((s * 2 + 1) * 2 + 0) * 64 + l];
        short8 b11 = Bs[((s * 2 + 1) * 2 + 1) * 64 + l];
        acc0 = __builtin_amdgcn_mfma_f32_16x16x32_bf16(A0[s], b00, acc0, 0, 0, 0);
        acc1 = __builtin_amdgcn_mfma_f32_16x16x32_bf16(A0[s], b01, acc1, 0, 0, 0);
        acc0 = __builtin_amdgcn_mfma_f32_16x16x32_bf16(A1[s], b10, acc0, 0, 0, 0);
        acc1 = __builtin_amdgcn_mfma_f32_16x16x32_bf16(A1[s], b11, acc1, 0, 0, 0);
    }

    int orow0 = mtile * 16 + kg * 4;
#pragma unroll
    for (int r = 0; r < 4; ++r) {
        size_t orow = (size_t)(orow0 + r) * kCout;
        out[orow + m]      = fmaxf(acc0[r] + bs0, 0.f);
        out[orow + 16 + m] = fmaxf(acc1[r] + bs1, 0.f);
    }
}

extern "C" void kernel_launch(void* const* d_in, const int* in_sizes, int n_in,
                              void* d_out, int out_size, void* d_ws, size_t ws_size,
                              hipStream_t stream) {
    const float* x    = (const float*)d_in[0];
    const float* val  = (const float*)d_in[1];
    const float* W    = (const float*)d_in[2];
    const float* bias = (const float*)d_in[3];
    const int* row     = (const int*)d_in[4];
    const int* col     = (const int*)d_in[5];
    const int* indices = (const int*)d_in[6];
    float* out = (float*)d_out;

    char* wsb = (char*)d_ws;
    unsigned short* poolb = (unsigned short*)(wsb + kOffPool);
    unsigned short* wfrag = (unsigned short*)(wsb + kOffWfrag);
    int* cursor  = (int*)(wsb + kOffCur);
    uint2* bucket = (uint2*)(wsb + kOffBucket);

    zero_kernel<<<(kNUp + 255) / 256, 256, 0, stream>>>(cursor);

    constexpr int prep_blocks = kWFragN / 256 + (kE + 255) / 256;  // 72 + 331
    prep_kernel<<<prep_blocks, 256, 0, stream>>>(W, wfrag, row, col, val, cursor, bucket);

    pool_gather<<<kNUp / 4, 256, 0, stream>>>(x, cursor, bucket, poolb);

    gemm_mfma<<<(kMRows / 16) / 4, 256, 0, stream>>>(poolb, wfrag, bias, indices, out);
}